// Round 4
// baseline (584.631 us; speedup 1.0000x reference)
//
#include <hip/hip_runtime.h>

#define RESO 192
#define DATA_DIM 28            // BASIS_DIM*3 + 1
#define BSHIFT 4               // 16 grid cells per bucket side
#define NBS ((RESO + (1 << BSHIFT) - 1) >> BSHIFT)   // 12
#define NBUCKETS (NBS * NBS * NBS)                   // 1728

typedef float f4 __attribute__((ext_vector_type(4)));

__device__ __forceinline__ void cell_of(float px, float py, float pz,
                                        const float* __restrict__ offset,
                                        const float* __restrict__ scaling,
                                        int& lx, int& ly, int& lz,
                                        float& p0, float& p1, float& p2) {
    const float g = (float)RESO;
    p0 = px * (scaling[0] * g) + (offset[0] * g - 0.5f);
    p1 = py * (scaling[1] * g) + (offset[1] * g - 0.5f);
    p2 = pz * (scaling[2] * g) + (offset[2] * g - 0.5f);
    p0 = fminf(fmaxf(p0, 0.0f), g - 1.0f);
    p1 = fminf(fmaxf(p1, 0.0f), g - 1.0f);
    p2 = fminf(fmaxf(p2, 0.0f), g - 1.0f);
    lx = min((int)p0, RESO - 2);
    ly = min((int)p1, RESO - 2);
    lz = min((int)p2, RESO - 2);
}

__global__ void zero_kernel(int* __restrict__ counts) {
    int i = blockIdx.x * blockDim.x + threadIdx.x;
    if (i < NBUCKETS) counts[i] = 0;
}

__global__ __launch_bounds__(256) void count_kernel(
    const float* __restrict__ pts, const float* __restrict__ offset,
    const float* __restrict__ scaling, int* __restrict__ counts, int npts) {
    int i = blockIdx.x * blockDim.x + threadIdx.x;
    if (i >= npts) return;
    int lx, ly, lz; float p0, p1, p2;
    cell_of(pts[i * 3], pts[i * 3 + 1], pts[i * 3 + 2], offset, scaling,
            lx, ly, lz, p0, p1, p2);
    int key = ((lx >> BSHIFT) * NBS + (ly >> BSHIFT)) * NBS + (lz >> BSHIFT);
    atomicAdd(counts + key, 1);
}

// Single-block exclusive scan over NBUCKETS (=1728) counters, in place.
__global__ __launch_bounds__(256) void scan_kernel(int* __restrict__ counts) {
    __shared__ int part[256];
    const int T = 256;
    const int C = (NBUCKETS + T - 1) / T;   // 7
    int t = threadIdx.x;
    int local[(NBUCKETS + 255) / 256];
    int s = 0;
    for (int j = 0; j < C; ++j) {
        int idx = t * C + j;
        int v = (idx < NBUCKETS) ? counts[idx] : 0;
        local[j] = s;
        s += v;
    }
    part[t] = s;
    __syncthreads();
    for (int off = 1; off < T; off <<= 1) {
        int v = (t >= off) ? part[t - off] : 0;
        __syncthreads();
        part[t] += v;
        __syncthreads();
    }
    int base = (t == 0) ? 0 : part[t - 1];
    for (int j = 0; j < C; ++j) {
        int idx = t * C + j;
        if (idx < NBUCKETS) counts[idx] = base + local[j];
    }
}

__global__ __launch_bounds__(256) void scatter_kernel(
    const float* __restrict__ pts, const float* __restrict__ offset,
    const float* __restrict__ scaling, int* __restrict__ offsets,
    f4* __restrict__ sorted, int npts) {
    int i = blockIdx.x * blockDim.x + threadIdx.x;
    if (i >= npts) return;
    float px = pts[i * 3], py = pts[i * 3 + 1], pz = pts[i * 3 + 2];
    int lx, ly, lz; float p0, p1, p2;
    cell_of(px, py, pz, offset, scaling, lx, ly, lz, p0, p1, p2);
    int key = ((lx >> BSHIFT) * NBS + (ly >> BSHIFT)) * NBS + (lz >> BSHIFT);
    int pos = atomicAdd(offsets + key, 1);
    f4 v = {px, py, pz, __int_as_float(i)};
    sorted[pos] = v;
}

// One point per 8-lane group; lane j (< 7) owns channels 4j..4j+3 (float4).
// Points arrive in bucket (spatially sorted) order -> data gathers L2-hit.
__global__ __launch_bounds__(256) void gather_kernel(
    const f4* __restrict__ sorted,
    const float* __restrict__ data,
    const int*   __restrict__ links,
    const float* __restrict__ offset,
    const float* __restrict__ scaling,
    float*       __restrict__ out,
    int npts)
{
    const int gid   = blockIdx.x * blockDim.x + threadIdx.x;
    const int point = gid >> 3;
    const int sub   = threadIdx.x & 7;
    if (point >= npts) return;

    const f4 s = sorted[point];            // broadcast within the 8-lane group
    const int orig = __float_as_int(s.w);

    int lx, ly, lz; float p0, p1, p2;
    cell_of(s.x, s.y, s.z, offset, scaling, lx, ly, lz, p0, p1, p2);

    const float wbx = p0 - (float)lx, wax = 1.0f - wbx;
    const float wby = p1 - (float)ly, way = 1.0f - wby;
    const float wbz = p2 - (float)lz, waz = 1.0f - wbz;

    const int base = (lx * RESO + ly) * RESO + lz;
    const int lk000 = links[base];
    const int lk001 = links[base + 1];
    const int lk010 = links[base + RESO];
    const int lk011 = links[base + RESO + 1];
    const int lk100 = links[base + RESO * RESO];
    const int lk101 = links[base + RESO * RESO + 1];
    const int lk110 = links[base + RESO * RESO + RESO];
    const int lk111 = links[base + RESO * RESO + RESO + 1];

    if (sub >= 7) return;   // lanes 0..6 cover 28 channels

    const float w000 = wax * way * waz;
    const float w001 = wax * way * wbz;
    const float w010 = wax * wby * waz;
    const float w011 = wax * wby * wbz;
    const float w100 = wbx * way * waz;
    const float w101 = wbx * way * wbz;
    const float w110 = wbx * wby * waz;
    const float w111 = wbx * wby * wbz;

    const int ch = sub * 4;

    f4 acc = {0.f, 0.f, 0.f, 0.f};

    #define CORNER(LK, W)                                                     \
        if ((LK) >= 0) {                                                      \
            const f4 v = *reinterpret_cast<const f4*>(                        \
                data + (size_t)(LK) * DATA_DIM + ch);                         \
            acc += (W) * v;                                                   \
        }

    CORNER(lk000, w000)
    CORNER(lk001, w001)
    CORNER(lk010, w010)
    CORNER(lk011, w011)
    CORNER(lk100, w100)
    CORNER(lk101, w101)
    CORNER(lk110, w110)
    CORNER(lk111, w111)
    #undef CORNER

    __builtin_nontemporal_store(acc,
        reinterpret_cast<f4*>(out + (size_t)orig * DATA_DIM + ch));
}

// Fallback (unsorted) path if d_ws is too small.
__global__ __launch_bounds__(256) void trilerp_direct(
    const float* __restrict__ points,
    const float* __restrict__ data,
    const int*   __restrict__ links,
    const float* __restrict__ offset,
    const float* __restrict__ scaling,
    float*       __restrict__ out,
    int npts)
{
    const int gid   = blockIdx.x * blockDim.x + threadIdx.x;
    const int point = gid >> 3;
    const int sub   = threadIdx.x & 7;
    if (point >= npts) return;

    int lx, ly, lz; float p0, p1, p2;
    cell_of(points[point * 3], points[point * 3 + 1], points[point * 3 + 2],
            offset, scaling, lx, ly, lz, p0, p1, p2);

    const float wbx = p0 - (float)lx, wax = 1.0f - wbx;
    const float wby = p1 - (float)ly, way = 1.0f - wby;
    const float wbz = p2 - (float)lz, waz = 1.0f - wbz;

    const int base = (lx * RESO + ly) * RESO + lz;
    const int lk000 = links[base];
    const int lk001 = links[base + 1];
    const int lk010 = links[base + RESO];
    const int lk011 = links[base + RESO + 1];
    const int lk100 = links[base + RESO * RESO];
    const int lk101 = links[base + RESO * RESO + 1];
    const int lk110 = links[base + RESO * RESO + RESO];
    const int lk111 = links[base + RESO * RESO + RESO + 1];

    if (sub >= 7) return;

    const float w000 = wax * way * waz;
    const float w001 = wax * way * wbz;
    const float w010 = wax * wby * waz;
    const float w011 = wax * wby * wbz;
    const float w100 = wbx * way * waz;
    const float w101 = wbx * way * wbz;
    const float w110 = wbx * wby * waz;
    const float w111 = wbx * wby * wbz;

    const int ch = sub * 4;
    f4 acc = {0.f, 0.f, 0.f, 0.f};

    #define CORNER(LK, W)                                                     \
        if ((LK) >= 0) {                                                      \
            const f4 v = *reinterpret_cast<const f4*>(                        \
                data + (size_t)(LK) * DATA_DIM + ch);                         \
            acc += (W) * v;                                                   \
        }
    CORNER(lk000, w000)
    CORNER(lk001, w001)
    CORNER(lk010, w010)
    CORNER(lk011, w011)
    CORNER(lk100, w100)
    CORNER(lk101, w101)
    CORNER(lk110, w110)
    CORNER(lk111, w111)
    #undef CORNER

    __builtin_nontemporal_store(acc,
        reinterpret_cast<f4*>(out + (size_t)point * DATA_DIM + ch));
}

extern "C" void kernel_launch(void* const* d_in, const int* in_sizes, int n_in,
                              void* d_out, int out_size, void* d_ws, size_t ws_size,
                              hipStream_t stream) {
    const float* points  = (const float*)d_in[0];
    const float* data    = (const float*)d_in[1];
    const int*   links   = (const int*)d_in[2];
    const float* offset  = (const float*)d_in[3];
    const float* scaling = (const float*)d_in[4];
    float* out = (float*)d_out;

    const int npts = in_sizes[0] / 3;

    const size_t need = (size_t)NBUCKETS * sizeof(int) + (size_t)npts * sizeof(f4);
    if (ws_size < need) {
        const int blocks = (npts + 31) / 32;
        trilerp_direct<<<blocks, 256, 0, stream>>>(points, data, links, offset,
                                                   scaling, out, npts);
        return;
    }

    int* counts = (int*)d_ws;                     // NBUCKETS ints (6912 B, 16B-mult)
    f4*  sorted = (f4*)((char*)d_ws + (size_t)NBUCKETS * sizeof(int));

    const int pblocks = (npts + 255) / 256;

    zero_kernel<<<(NBUCKETS + 255) / 256, 256, 0, stream>>>(counts);
    count_kernel<<<pblocks, 256, 0, stream>>>(points, offset, scaling, counts, npts);
    scan_kernel<<<1, 256, 0, stream>>>(counts);
    scatter_kernel<<<pblocks, 256, 0, stream>>>(points, offset, scaling, counts,
                                                sorted, npts);

    const int gblocks = (npts + 31) / 32;         // 8 lanes per point
    gather_kernel<<<gblocks, 256, 0, stream>>>(sorted, data, links, offset,
                                               scaling, out, npts);
}

// Round 5
// 229.169 us; speedup vs baseline: 2.5511x; 2.5511x over previous
//
#include <hip/hip_runtime.h>

#define RESO 192
#define DATA_DIM 28   // BASIS_DIM*3 + 1 = 28

typedef float f4 __attribute__((ext_vector_type(4)));

// One point per 8-lane group; lane j (< 7) owns channels 4j..4j+3 (float4).
// All 8 corner gathers issue unconditionally (invalid links alias row 0,
// which stays cache-hot) with the weight zeroed instead -> no exec-mask
// regions, maximum memory-level parallelism.
__global__ __launch_bounds__(256) void trilerp_kernel(
    const float* __restrict__ points,
    const float* __restrict__ data,
    const int*   __restrict__ links,
    const float* __restrict__ offset,
    const float* __restrict__ scaling,
    float*       __restrict__ out,
    int npts)
{
    const int gid   = blockIdx.x * blockDim.x + threadIdx.x;
    const int point = gid >> 3;
    const int sub   = threadIdx.x & 7;
    if (point >= npts) return;

    // Same address across the 8-lane group -> broadcast-coalesced
    const float px = points[point * 3 + 0];
    const float py = points[point * 3 + 1];
    const float pz = points[point * 3 + 2];

    const float g = (float)RESO;

    float p0 = px * (scaling[0] * g) + (offset[0] * g - 0.5f);
    float p1 = py * (scaling[1] * g) + (offset[1] * g - 0.5f);
    float p2 = pz * (scaling[2] * g) + (offset[2] * g - 0.5f);

    p0 = fminf(fmaxf(p0, 0.0f), g - 1.0f);
    p1 = fminf(fmaxf(p1, 0.0f), g - 1.0f);
    p2 = fminf(fmaxf(p2, 0.0f), g - 1.0f);

    const int lx = min((int)p0, RESO - 2);
    const int ly = min((int)p1, RESO - 2);
    const int lz = min((int)p2, RESO - 2);

    const float wbx = p0 - (float)lx, wax = 1.0f - wbx;
    const float wby = p1 - (float)ly, way = 1.0f - wby;
    const float wbz = p2 - (float)lz, waz = 1.0f - wbz;

    const int base = (lx * RESO + ly) * RESO + lz;
    const int lk000 = links[base];
    const int lk001 = links[base + 1];
    const int lk010 = links[base + RESO];
    const int lk011 = links[base + RESO + 1];
    const int lk100 = links[base + RESO * RESO];
    const int lk101 = links[base + RESO * RESO + 1];
    const int lk110 = links[base + RESO * RESO + RESO];
    const int lk111 = links[base + RESO * RESO + RESO + 1];

    if (sub >= 7) return;   // lanes 0..6 cover 28 channels

    const int ch = sub * 4;   // first channel this lane owns

    // Unconditional gathers from clamped row index (row 0 stays hot).
    #define LOADC(LK) \
        *reinterpret_cast<const f4*>(data + (size_t)(max(LK, 0) * DATA_DIM + ch))
    const f4 v000 = LOADC(lk000);
    const f4 v001 = LOADC(lk001);
    const f4 v010 = LOADC(lk010);
    const f4 v011 = LOADC(lk011);
    const f4 v100 = LOADC(lk100);
    const f4 v101 = LOADC(lk101);
    const f4 v110 = LOADC(lk110);
    const f4 v111 = LOADC(lk111);
    #undef LOADC

    // Weights, zeroed for invalid corners (branchless cndmask)
    const float w000 = (lk000 >= 0) ? wax * way * waz : 0.0f;
    const float w001 = (lk001 >= 0) ? wax * way * wbz : 0.0f;
    const float w010 = (lk010 >= 0) ? wax * wby * waz : 0.0f;
    const float w011 = (lk011 >= 0) ? wax * wby * wbz : 0.0f;
    const float w100 = (lk100 >= 0) ? wbx * way * waz : 0.0f;
    const float w101 = (lk101 >= 0) ? wbx * way * wbz : 0.0f;
    const float w110 = (lk110 >= 0) ? wbx * wby * waz : 0.0f;
    const float w111 = (lk111 >= 0) ? wbx * wby * wbz : 0.0f;

    f4 acc = w000 * v000;
    acc += w001 * v001;
    acc += w010 * v010;
    acc += w011 * v011;
    acc += w100 * v100;
    acc += w101 * v101;
    acc += w110 * v110;
    acc += w111 * v111;

    // Streaming store; keep L2/L3 for the data table
    __builtin_nontemporal_store(acc,
        reinterpret_cast<f4*>(out + (size_t)point * DATA_DIM + ch));
}

extern "C" void kernel_launch(void* const* d_in, const int* in_sizes, int n_in,
                              void* d_out, int out_size, void* d_ws, size_t ws_size,
                              hipStream_t stream) {
    const float* points  = (const float*)d_in[0];
    const float* data    = (const float*)d_in[1];
    const int*   links   = (const int*)d_in[2];
    const float* offset  = (const float*)d_in[3];
    const float* scaling = (const float*)d_in[4];
    float* out = (float*)d_out;

    const int npts = in_sizes[0] / 3;

    // 8 lanes per point, 256 threads/block -> 32 points per block
    const int blocks = (npts + 31) / 32;
    trilerp_kernel<<<blocks, 256, 0, stream>>>(points, data, links, offset,
                                               scaling, out, npts);
}